// Round 2
// baseline (10278.587 us; speedup 1.0000x reference)
//
#include <hip/hip_runtime.h>

#define T_STEPS 512
#define BATCH   256
#define N_INP   128
#define N_HID   512
#define N_OUT   10
#define K_DIM   1152   // N_INP + 2*N_HID

#define DT_C     0.042f
#define GAMMA_C  2.7f
#define EPS_C    4.7f

#define NWG        128     // 8 m-groups (32 rows) x 16 n-tiles (32 cols)
#define GROUP_WGS  16      // WGs per row-group (share one barrier)
#define WG_THREADS 256

typedef short          s16x8  __attribute__((ext_vector_type(8)));
typedef float          f32x16 __attribute__((ext_vector_type(16)));
typedef float          f32x4  __attribute__((ext_vector_type(4)));
typedef unsigned short u16x4  __attribute__((ext_vector_type(4)));

__device__ inline unsigned short f2bf(float f) {
  union { float f; unsigned u; } v; v.f = f;
  unsigned r = v.u + 0x7fffu + ((v.u >> 16) & 1u);   // RNE
  return (unsigned short)(r >> 16);
}
__device__ inline float bf2f(unsigned short h) {
  union { unsigned u; float f; } v; v.u = ((unsigned)h) << 16;
  return v.f;
}

// Monotonic-epoch barrier over GROUP_WGS workgroups (one per row-group).
// Release: __syncthreads drains this WG's vmem (vmcnt(0)), then agent fence
// (wb L2) before the arrive-add. Acquire: agent fence (inv) after the wait so
// post-barrier loads see other CUs'/XCDs' publishes.
__device__ inline void group_barrier(unsigned* cnt, unsigned* epoch, unsigned e) {
  __syncthreads();
  if (threadIdx.x == 0) {
    __threadfence();   // seq_cst agent fence: write-back prior stores
    unsigned a = __hip_atomic_fetch_add(cnt, 1u, __ATOMIC_ACQ_REL, __HIP_MEMORY_SCOPE_AGENT);
    if (a == GROUP_WGS - 1) {
      __hip_atomic_store(cnt, 0u, __ATOMIC_RELAXED, __HIP_MEMORY_SCOPE_AGENT);
      __hip_atomic_store(epoch, e, __ATOMIC_RELEASE, __HIP_MEMORY_SCOPE_AGENT);
    } else {
      while (__hip_atomic_load(epoch, __ATOMIC_ACQUIRE, __HIP_MEMORY_SCOPE_AGENT) < e) {
        __builtin_amdgcn_s_sleep(1);
      }
    }
  }
  __syncthreads();
  __builtin_amdgcn_fence(__ATOMIC_SEQ_CST, "agent");  // inv caches before re-reading state
}

// Persistent recurrent kernel (plain launch; 128 blocks <= 256 CUs => co-resident).
// Hbf: double-buffered published state, bf16 [2][256][1024]; cols 0..511 = hz,
//      512..1023 = hy  (concat k-index = 128+col for hz, 640+(col-512) for hy).
// Hy32: final hy in fp32 [256][512] for the output GEMM.
__global__ __launch_bounds__(WG_THREADS, 1) void cornn_kernel(
    const float* __restrict__ x, const float* __restrict__ W,
    const float* __restrict__ bias, unsigned short* __restrict__ Hbf,
    float* __restrict__ Hy32, unsigned* __restrict__ barrier_ws) {
  const int tid   = threadIdx.x;
  const int lane  = tid & 63;
  const int ks    = tid >> 6;        // k-split wave id 0..3 (288 k each)
  const int half  = lane >> 5;       // A/B frag k-half
  const int half8 = half << 3;
  const int lcol  = lane & 31;
  const int mi    = blockIdx.x & 7;  // row group  (XCD-aligned: blockIdx%8)
  const int ni    = blockIdx.x >> 3; // col tile
  const int rowA  = (mi << 5) + lcol;  // batch row for A frags

  unsigned* cnt   = barrier_ws + mi * 64;        // 256 B per group (no false sharing)
  unsigned* epoch = barrier_ws + mi * 64 + 32;

  __shared__ float sC[4][1024];   // K-split partials, 16 KB
  __shared__ float sHz[1024];     // fp32 state (32 rows x 32 cols)
  __shared__ float sHy[1024];
  __shared__ float sB[32];

  // ---- stage W fragments into registers (hi/lo bf16 split), once ----
  s16x8 whi[18], wlo[18];
  {
    const int wcol = (ni << 5) + lcol;
    #pragma unroll
    for (int i = 0; i < 18; ++i) {
      const int kb = ks * 288 + i * 16 + half8;
      const float* wp = W + (size_t)kb * N_HID + wcol;   // W is [1152][512] row-major
      s16x8 hi, lo;
      #pragma unroll
      for (int j = 0; j < 8; ++j) {
        float f = wp[(size_t)j * N_HID];                 // coalesced across lanes 0..31
        unsigned short h = f2bf(f);
        hi[j] = (short)h;
        lo[j] = (short)f2bf(f - bf2f(h));
      }
      whi[i] = hi; wlo[i] = lo;
    }
  }
  if (tid < 32) sB[tid] = bias[(ni << 5) + tid];

  // ---- zero state + publish zeros to read-buffer 0 ----
  {
    const int e0   = tid << 2;
    const int rowL = e0 >> 5, c0 = e0 & 31;
    const int rowG = (mi << 5) + rowL;
    const int colG = (ni << 5) + c0;
    f32x4 z = {0.f, 0.f, 0.f, 0.f};
    *reinterpret_cast<f32x4*>(&sHz[e0]) = z;
    *reinterpret_cast<f32x4*>(&sHy[e0]) = z;
    u16x4 zh = {0, 0, 0, 0};
    *reinterpret_cast<u16x4*>(Hbf + (size_t)rowG * 1024 + colG)       = zh;
    *reinterpret_cast<u16x4*>(Hbf + (size_t)rowG * 1024 + 512 + colG) = zh;
  }
  unsigned ep = 1;
  group_barrier(cnt, epoch, ep++);

  for (int t = 0; t < T_STEPS; ++t) {
    const unsigned short* rbuf = Hbf + (size_t)(t & 1) * (256 * 1024);
    unsigned short*       wbuf = Hbf + (size_t)((t & 1) ^ 1) * (256 * 1024);

    f32x16 acc = {};
    const float* xrow = x + (size_t)t * (BATCH * N_INP) + (size_t)rowA * N_INP;
    const unsigned short* hrow = rbuf + (size_t)rowA * 1024;

    #pragma unroll
    for (int i = 0; i < 18; ++i) {
      const int k0 = ks * 288 + i * 16;
      if (ks == 0 && i < 8) {
        // x part (fp32 input): hi/lo split for full precision
        const float* xp = xrow + k0 + half8;
        f32x4 a0 = *reinterpret_cast<const f32x4*>(xp);
        f32x4 a1 = *reinterpret_cast<const f32x4*>(xp + 4);
        s16x8 ahi, alo;
        #pragma unroll
        for (int j = 0; j < 4; ++j) {
          float f0 = a0[j], f1 = a1[j];
          unsigned short h0 = f2bf(f0), h1 = f2bf(f1);
          ahi[j]     = (short)h0;  ahi[j + 4] = (short)h1;
          alo[j]     = (short)f2bf(f0 - bf2f(h0));
          alo[j + 4] = (short)f2bf(f1 - bf2f(h1));
        }
        acc = __builtin_amdgcn_mfma_f32_32x32x16_bf16(ahi, whi[i], acc, 0, 0, 0);
        acc = __builtin_amdgcn_mfma_f32_32x32x16_bf16(ahi, wlo[i], acc, 0, 0, 0);
        acc = __builtin_amdgcn_mfma_f32_32x32x16_bf16(alo, whi[i], acc, 0, 0, 0);
      } else {
        // recurrent part: published bf16 state, 16B aligned loads
        const s16x8 a = *reinterpret_cast<const s16x8*>(hrow + (k0 - 128) + half8);
        acc = __builtin_amdgcn_mfma_f32_32x32x16_bf16(a, whi[i], acc, 0, 0, 0);
        acc = __builtin_amdgcn_mfma_f32_32x32x16_bf16(a, wlo[i], acc, 0, 0, 0);
      }
    }

    // write K-split partials (C/D layout: col=lane&31, row=(r&3)+8*(r>>2)+4*half)
    #pragma unroll
    for (int r = 0; r < 16; ++r) {
      const int rowL = (r & 3) + ((r >> 2) << 3) + (half << 2);
      sC[ks][rowL * 32 + lcol] = acc[r];
    }
    __syncthreads();

    // reduce + tanh + state update + publish
    {
      const int e0   = tid << 2;
      const int rowL = e0 >> 5, c0 = e0 & 31;
      const int rowG = (mi << 5) + rowL;
      const int colG = (ni << 5) + c0;
      f32x4 s = *reinterpret_cast<f32x4*>(&sC[0][e0]);
      s += *reinterpret_cast<f32x4*>(&sC[1][e0]);
      s += *reinterpret_cast<f32x4*>(&sC[2][e0]);
      s += *reinterpret_cast<f32x4*>(&sC[3][e0]);
      f32x4 hz = *reinterpret_cast<f32x4*>(&sHz[e0]);
      f32x4 hy = *reinterpret_cast<f32x4*>(&sHy[e0]);
      u16x4 pz, py;
      #pragma unroll
      for (int j = 0; j < 4; ++j) {
        float pre = tanhf(s[j] + sB[c0 + j]);
        float z = hz[j] + DT_C * (pre - GAMMA_C * hy[j] - EPS_C * hz[j]);
        float y = hy[j] + DT_C * z;
        hz[j] = z; hy[j] = y;
        pz[j] = f2bf(z); py[j] = f2bf(y);
      }
      *reinterpret_cast<f32x4*>(&sHz[e0]) = hz;
      *reinterpret_cast<f32x4*>(&sHy[e0]) = hy;
      *reinterpret_cast<u16x4*>(wbuf + (size_t)rowG * 1024 + colG)       = pz;
      *reinterpret_cast<u16x4*>(wbuf + (size_t)rowG * 1024 + 512 + colG) = py;
      if (t == T_STEPS - 1 && Hy32 != nullptr) {
        *reinterpret_cast<f32x4*>(Hy32 + (size_t)rowG * 512 + colG) = hy;
      }
    }
    if (t < T_STEPS - 1) group_barrier(cnt, epoch, ep++);
  }
}

// out[b][c] = sum_k hy[b][k] * Wout[k][c] + bout[c]
__global__ void cornn_out_kernel(const float* __restrict__ Hy32,
                                 const unsigned short* __restrict__ HbfFinal,
                                 const float* __restrict__ Wout,
                                 const float* __restrict__ bout,
                                 float* __restrict__ out) {
  const int b = blockIdx.x;
  const int lane = threadIdx.x;   // 64 threads
  float a[N_OUT];
  #pragma unroll
  for (int c = 0; c < N_OUT; ++c) a[c] = 0.f;
  #pragma unroll
  for (int j = 0; j < 8; ++j) {
    const int k = lane + (j << 6);
    const float h = Hy32 ? Hy32[(size_t)b * N_HID + k]
                         : bf2f(HbfFinal[(size_t)b * 1024 + 512 + k]);
    const float* wr = Wout + (size_t)k * N_OUT;
    #pragma unroll
    for (int c = 0; c < N_OUT; ++c) a[c] += h * wr[c];
  }
  #pragma unroll
  for (int c = 0; c < N_OUT; ++c) {
    float v = a[c];
    for (int off = 32; off > 0; off >>= 1) v += __shfl_down(v, off, 64);
    if (lane == 0) out[(size_t)b * N_OUT + c] = v + bout[c];
  }
}

extern "C" void kernel_launch(void* const* d_in, const int* in_sizes, int n_in,
                              void* d_out, int out_size, void* d_ws, size_t ws_size,
                              hipStream_t stream) {
  (void)in_sizes; (void)n_in; (void)out_size;
  const float* x    = (const float*)d_in[0];
  const float* W    = (const float*)d_in[1];
  const float* bias = (const float*)d_in[2];
  const float* Wout = (const float*)d_in[3];
  const float* bout = (const float*)d_in[4];

  char* ws = (char*)d_ws;
  unsigned*       bar  = (unsigned*)ws;                       // 4 KiB barrier area
  unsigned short* Hbf  = (unsigned short*)(ws + 4096);        // 2 x 256 x 1024 bf16 = 1 MiB
  float*          Hy32 = (float*)(ws + 4096 + (size_t)2 * 256 * 1024 * 2);
  const size_t needed = 4096 + (size_t)2 * 256 * 1024 * 2 + (size_t)256 * 512 * 4;
  float* hyPtr = (ws_size >= needed) ? Hy32 : nullptr;

  hipMemsetAsync(bar, 0, 4096, stream);   // barrier cnt/epoch = 0 (ws is poisoned 0xAA)

  cornn_kernel<<<dim3(NWG), dim3(WG_THREADS), 0, stream>>>(x, W, bias, Hbf, hyPtr, bar);

  cornn_out_kernel<<<dim3(BATCH), dim3(64), 0, stream>>>(hyPtr, Hbf, Wout, bout,
                                                         (float*)d_out);
}

// Round 3
// 4753.275 us; speedup vs baseline: 2.1624x; 2.1624x over previous
//
#include <hip/hip_runtime.h>

#define T_STEPS 512
#define BATCH   256
#define N_INP   128
#define N_HID   512
#define N_OUT   10
#define K_DIM   1152   // N_INP + 2*N_HID

#define DT_C     0.042f
#define GAMMA_C  2.7f
#define EPS_C    4.7f

#define NWG        128     // 8 m-groups (32 rows) x 16 n-tiles (32 cols)
#define GROUP_WGS  16      // WGs per row-group (share one flag set)
#define WG_THREADS 256

typedef short          s16x8  __attribute__((ext_vector_type(8)));
typedef float          f32x16 __attribute__((ext_vector_type(16)));
typedef float          f32x4  __attribute__((ext_vector_type(4)));
typedef unsigned short u16x4  __attribute__((ext_vector_type(4)));
typedef unsigned long long u64;

__device__ inline unsigned short f2bf(float f) {
  union { float f; unsigned u; } v; v.f = f;
  unsigned r = v.u + 0x7fffu + ((v.u >> 16) & 1u);   // RNE
  return (unsigned short)(r >> 16);
}
__device__ inline float bf2f(unsigned short h) {
  union { unsigned u; float f; } v; v.u = ((unsigned)h) << 16;
  return v.f;
}

// Flag barrier over GROUP_WGS workgroups, built on agent-scope RELAXED atomics
// (sc1: bypass L2, read/write the Infinity Cache = cross-XCD coherence point).
// No buffer_wbl2 anywhere: all coherence-critical stores are sc1 write-through,
// so release only needs vmcnt drain (done by __syncthreads before the flag
// store). One ACQUIRE agent fence (buffer_inv, tag-invalidate only) after the
// poll makes the plain 16B state reloads refetch fresh lines from IC.
__device__ inline void flag_barrier(unsigned* gflags, int ni, unsigned ep, int tid) {
  __syncthreads();   // s_waitcnt vmcnt(0): sc1 publishes acked at coherence point
  if (tid == 0) {
    __hip_atomic_store(&gflags[ni], ep, __ATOMIC_RELAXED, __HIP_MEMORY_SCOPE_AGENT);
  }
  if (tid < 64) {
    const int l = tid & 15;
    for (;;) {
      unsigned v = __hip_atomic_load(&gflags[l], __ATOMIC_RELAXED, __HIP_MEMORY_SCOPE_AGENT);
      if (__ballot(v >= ep) == ~0ull) break;
    }
  }
  __syncthreads();
  __builtin_amdgcn_fence(__ATOMIC_ACQUIRE, "agent");   // buffer_inv (no writeback)
}

__device__ inline void publish8(unsigned short* p, u16x4 v) {
  union { u16x4 v; u64 q; } u; u.v = v;
  __hip_atomic_store((u64*)p, u.q, __ATOMIC_RELAXED, __HIP_MEMORY_SCOPE_AGENT);
}

// Persistent recurrent kernel (plain launch; 128 blocks <= 256 CUs => co-resident).
// Hbf: double-buffered published state, bf16 [2][256][1024]; cols 0..511 = hz,
//      512..1023 = hy  (concat k-index = 128+col for hz, 640+(col-512) for hy).
// Hy32: final hy in fp32 [256][512] for the output GEMM.
__global__ __launch_bounds__(WG_THREADS, 1) void cornn_kernel(
    const float* __restrict__ x, const float* __restrict__ W,
    const float* __restrict__ bias, unsigned short* __restrict__ Hbf,
    float* __restrict__ Hy32, unsigned* __restrict__ flags_ws) {
  const int tid   = threadIdx.x;
  const int lane  = tid & 63;
  const int ks    = tid >> 6;        // k-split wave id 0..3 (288 k each)
  const int half  = lane >> 5;       // A/B frag k-half
  const int half8 = half << 3;
  const int lcol  = lane & 31;
  const int mi    = blockIdx.x & 7;  // row group  (XCD-aligned: blockIdx%8)
  const int ni    = blockIdx.x >> 3; // col tile
  const int rowA  = (mi << 5) + lcol;  // batch row for A frags

  unsigned* gflags = flags_ws + mi * 64;   // 16 dwords used, 256B stride per group

  __shared__ float sC[4][1024];   // K-split partials, 16 KB
  __shared__ float sHz[1024];     // fp32 state (32 rows x 32 cols)
  __shared__ float sHy[1024];
  __shared__ float sB[32];

  // ---- stage W fragments into registers (hi/lo bf16 split), once ----
  s16x8 whi[18], wlo[18];
  {
    const int wcol = (ni << 5) + lcol;
    #pragma unroll
    for (int i = 0; i < 18; ++i) {
      const int kb = ks * 288 + i * 16 + half8;
      const float* wp = W + (size_t)kb * N_HID + wcol;   // W is [1152][512] row-major
      s16x8 hi, lo;
      #pragma unroll
      for (int j = 0; j < 8; ++j) {
        float f = wp[(size_t)j * N_HID];                 // coalesced across lanes 0..31
        unsigned short h = f2bf(f);
        hi[j] = (short)h;
        lo[j] = (short)f2bf(f - bf2f(h));
      }
      whi[i] = hi; wlo[i] = lo;
    }
  }
  if (tid < 32) sB[tid] = bias[(ni << 5) + tid];

  // ---- zero state + publish zeros to read-buffer 0 (sc1 stores) ----
  {
    const int e0   = tid << 2;
    const int rowL = e0 >> 5, c0 = e0 & 31;
    const int rowG = (mi << 5) + rowL;
    const int colG = (ni << 5) + c0;
    f32x4 z = {0.f, 0.f, 0.f, 0.f};
    *reinterpret_cast<f32x4*>(&sHz[e0]) = z;
    *reinterpret_cast<f32x4*>(&sHy[e0]) = z;
    u16x4 zh = {0, 0, 0, 0};
    publish8(Hbf + (size_t)rowG * 1024 + colG, zh);
    publish8(Hbf + (size_t)rowG * 1024 + 512 + colG, zh);
  }
  unsigned ep = 1;
  flag_barrier(gflags, ni, ep++, tid);

  for (int t = 0; t < T_STEPS; ++t) {
    const unsigned short* rbuf = Hbf + (size_t)(t & 1) * (256 * 1024);
    unsigned short*       wbuf = Hbf + (size_t)((t & 1) ^ 1) * (256 * 1024);

    f32x16 acc = {};
    const float* xrow = x + (size_t)t * (BATCH * N_INP) + (size_t)rowA * N_INP;
    const unsigned short* hrow = rbuf + (size_t)rowA * 1024;

    #pragma unroll
    for (int i = 0; i < 18; ++i) {
      const int k0 = ks * 288 + i * 16;
      if (ks == 0 && i < 8) {
        // x part (fp32 input): hi/lo split for full precision
        const float* xp = xrow + k0 + half8;
        f32x4 a0 = *reinterpret_cast<const f32x4*>(xp);
        f32x4 a1 = *reinterpret_cast<const f32x4*>(xp + 4);
        s16x8 ahi, alo;
        #pragma unroll
        for (int j = 0; j < 4; ++j) {
          float f0 = a0[j], f1 = a1[j];
          unsigned short h0 = f2bf(f0), h1 = f2bf(f1);
          ahi[j]     = (short)h0;  ahi[j + 4] = (short)h1;
          alo[j]     = (short)f2bf(f0 - bf2f(h0));
          alo[j + 4] = (short)f2bf(f1 - bf2f(h1));
        }
        acc = __builtin_amdgcn_mfma_f32_32x32x16_bf16(ahi, whi[i], acc, 0, 0, 0);
        acc = __builtin_amdgcn_mfma_f32_32x32x16_bf16(ahi, wlo[i], acc, 0, 0, 0);
        acc = __builtin_amdgcn_mfma_f32_32x32x16_bf16(alo, whi[i], acc, 0, 0, 0);
      } else {
        // recurrent part: published bf16 state, 16B plain loads (fresh via inv)
        const s16x8 a = *reinterpret_cast<const s16x8*>(hrow + (k0 - 128) + half8);
        acc = __builtin_amdgcn_mfma_f32_32x32x16_bf16(a, whi[i], acc, 0, 0, 0);
        acc = __builtin_amdgcn_mfma_f32_32x32x16_bf16(a, wlo[i], acc, 0, 0, 0);
      }
    }

    // write K-split partials (C/D layout: col=lane&31, row=(r&3)+8*(r>>2)+4*half)
    #pragma unroll
    for (int r = 0; r < 16; ++r) {
      const int rowL = (r & 3) + ((r >> 2) << 3) + (half << 2);
      sC[ks][rowL * 32 + lcol] = acc[r];
    }
    __syncthreads();

    // reduce + tanh + state update + publish (sc1 stores)
    {
      const int e0   = tid << 2;
      const int rowL = e0 >> 5, c0 = e0 & 31;
      const int rowG = (mi << 5) + rowL;
      const int colG = (ni << 5) + c0;
      f32x4 s = *reinterpret_cast<f32x4*>(&sC[0][e0]);
      s += *reinterpret_cast<f32x4*>(&sC[1][e0]);
      s += *reinterpret_cast<f32x4*>(&sC[2][e0]);
      s += *reinterpret_cast<f32x4*>(&sC[3][e0]);
      f32x4 hz = *reinterpret_cast<f32x4*>(&sHz[e0]);
      f32x4 hy = *reinterpret_cast<f32x4*>(&sHy[e0]);
      u16x4 pz, py;
      #pragma unroll
      for (int j = 0; j < 4; ++j) {
        float pre = tanhf(s[j] + sB[c0 + j]);
        float z = hz[j] + DT_C * (pre - GAMMA_C * hy[j] - EPS_C * hz[j]);
        float y = hy[j] + DT_C * z;
        hz[j] = z; hy[j] = y;
        pz[j] = f2bf(z); py[j] = f2bf(y);
      }
      *reinterpret_cast<f32x4*>(&sHz[e0]) = hz;
      *reinterpret_cast<f32x4*>(&sHy[e0]) = hy;
      publish8(wbuf + (size_t)rowG * 1024 + colG, pz);
      publish8(wbuf + (size_t)rowG * 1024 + 512 + colG, py);
      if (t == T_STEPS - 1 && Hy32 != nullptr) {
        *reinterpret_cast<f32x4*>(Hy32 + (size_t)rowG * 512 + colG) = hy;
      }
    }
    if (t < T_STEPS - 1) flag_barrier(gflags, ni, ep++, tid);
  }
}

// out[b][c] = sum_k hy[b][k] * Wout[k][c] + bout[c]
__global__ void cornn_out_kernel(const float* __restrict__ Hy32,
                                 const unsigned short* __restrict__ HbfFinal,
                                 const float* __restrict__ Wout,
                                 const float* __restrict__ bout,
                                 float* __restrict__ out) {
  const int b = blockIdx.x;
  const int lane = threadIdx.x;   // 64 threads
  float a[N_OUT];
  #pragma unroll
  for (int c = 0; c < N_OUT; ++c) a[c] = 0.f;
  #pragma unroll
  for (int j = 0; j < 8; ++j) {
    const int k = lane + (j << 6);
    const float h = Hy32 ? Hy32[(size_t)b * N_HID + k]
                         : bf2f(HbfFinal[(size_t)b * 1024 + 512 + k]);
    const float* wr = Wout + (size_t)k * N_OUT;
    #pragma unroll
    for (int c = 0; c < N_OUT; ++c) a[c] += h * wr[c];
  }
  #pragma unroll
  for (int c = 0; c < N_OUT; ++c) {
    float v = a[c];
    for (int off = 32; off > 0; off >>= 1) v += __shfl_down(v, off, 64);
    if (lane == 0) out[(size_t)b * N_OUT + c] = v + bout[c];
  }
}

extern "C" void kernel_launch(void* const* d_in, const int* in_sizes, int n_in,
                              void* d_out, int out_size, void* d_ws, size_t ws_size,
                              hipStream_t stream) {
  (void)in_sizes; (void)n_in; (void)out_size;
  const float* x    = (const float*)d_in[0];
  const float* W    = (const float*)d_in[1];
  const float* bias = (const float*)d_in[2];
  const float* Wout = (const float*)d_in[3];
  const float* bout = (const float*)d_in[4];

  char* ws = (char*)d_ws;
  unsigned*       flags = (unsigned*)ws;                      // 4 KiB flag area
  unsigned short* Hbf   = (unsigned short*)(ws + 4096);       // 2 x 256 x 1024 bf16 = 1 MiB
  float*          Hy32  = (float*)(ws + 4096 + (size_t)2 * 256 * 1024 * 2);
  const size_t needed = 4096 + (size_t)2 * 256 * 1024 * 2 + (size_t)256 * 512 * 4;
  float* hyPtr = (ws_size >= needed) ? Hy32 : nullptr;

  hipMemsetAsync(flags, 0, 4096, stream);   // flags = 0 (ws is poisoned 0xAA)

  cornn_kernel<<<dim3(NWG), dim3(WG_THREADS), 0, stream>>>(x, W, bias, Hbf, hyPtr, flags);

  cornn_out_kernel<<<dim3(BATCH), dim3(64), 0, stream>>>(hyPtr, Hbf, Wout, bout,
                                                         (float*)d_out);
}

// Round 4
// 3176.226 us; speedup vs baseline: 3.2361x; 1.4965x over previous
//
#include <hip/hip_runtime.h>

#define T_STEPS 512
#define BATCH   256
#define N_INP   128
#define N_HID   512
#define N_OUT   10

#define DT_C     0.042f
#define GAMMA_C  2.7f
#define EPS_C    4.7f

#define NWG        128     // 8 m-groups (32 rows) x 16 n-tiles (32 cols)
#define GROUP_WGS  16      // WGs per row-group (share one flag set)
#define WG_THREADS 256

typedef short          s16x8  __attribute__((ext_vector_type(8)));
typedef float          f32x16 __attribute__((ext_vector_type(16)));
typedef float          f32x4  __attribute__((ext_vector_type(4)));
typedef unsigned short u16x4  __attribute__((ext_vector_type(4)));
typedef unsigned long long u64;

__device__ inline unsigned short f2bf(float f) {
  union { float f; unsigned u; } v; v.f = f;
  unsigned r = v.u + 0x7fffu + ((v.u >> 16) & 1u);   // RNE
  return (unsigned short)(r >> 16);
}
__device__ inline float bf2f(unsigned short h) {
  union { unsigned u; float f; } v; v.u = ((unsigned)h) << 16;
  return v.f;
}

// agent-scope relaxed = sc1: bypasses L1/L2, hits the coherence point (IC).
__device__ inline void pub8(unsigned short* p, u16x4 v) {
  union { u16x4 v; u64 q; } u; u.v = v;
  __hip_atomic_store((u64*)p, u.q, __ATOMIC_RELAXED, __HIP_MEMORY_SCOPE_AGENT);
}
__device__ inline u64 ld8(const u64* p) {
  return __hip_atomic_load(p, __ATOMIC_RELAXED, __HIP_MEMORY_SCOPE_AGENT);
}

// x-part: chunks CI0..CI0+CNT-1 of the fp32 input, hi/lo bf16 split.
template<int CI0, int CNT>
__device__ inline void xpart(const float* xrow, int half8,
                             const s16x8* wxhi, const s16x8* wxlo, f32x16& acc) {
  #pragma unroll
  for (int i = 0; i < CNT; ++i) {
    const float* xp = xrow + (CI0 + i) * 16 + half8;
    f32x4 a0 = *reinterpret_cast<const f32x4*>(xp);
    f32x4 a1 = *reinterpret_cast<const f32x4*>(xp + 4);
    s16x8 ahi, alo;
    #pragma unroll
    for (int j = 0; j < 4; ++j) {
      float f0 = a0[j], f1 = a1[j];
      unsigned short h0 = f2bf(f0), h1 = f2bf(f1);
      ahi[j]     = (short)h0;  ahi[j + 4] = (short)h1;
      alo[j]     = (short)f2bf(f0 - bf2f(h0));
      alo[j + 4] = (short)f2bf(f1 - bf2f(h1));
    }
    acc = __builtin_amdgcn_mfma_f32_32x32x16_bf16(ahi, wxhi[i], acc, 0, 0, 0);
    acc = __builtin_amdgcn_mfma_f32_32x32x16_bf16(ahi, wxlo[i], acc, 0, 0, 0);
    acc = __builtin_amdgcn_mfma_f32_32x32x16_bf16(alo, wxhi[i], acc, 0, 0, 0);
  }
}

// Persistent recurrent kernel (plain launch; 128 blocks <= 256 CUs => co-resident).
// Hbf: double-buffered published state, bf16 [2][256][1024]; col c<512 = hz[c]
//      (W row 128+c), col 512+c = hy[c] (W row 640+c).
__global__ __launch_bounds__(WG_THREADS, 1) void cornn_kernel(
    const float* __restrict__ x, const float* __restrict__ W,
    const float* __restrict__ bias, unsigned short* __restrict__ Hbf,
    float* __restrict__ Hy32, unsigned* __restrict__ flags_ws) {
  const int tid   = threadIdx.x;
  const int lane  = tid & 63;
  const int ks    = tid >> 6;        // wave id 0..3
  const int half  = lane >> 5;       // A/B frag k-half
  const int half8 = half << 3;
  const int lcol  = lane & 31;
  const int mi    = blockIdx.x & 7;  // row group (XCD-aligned: blockIdx%8)
  const int ni    = blockIdx.x >> 3; // col tile
  const int rowA  = (mi << 5) + lcol;

  unsigned* gflags = flags_ws + mi * 64;   // 16 dwords per group, 256B stride

  __shared__ float sC[4][1024];   // K-split partials, 16 KB
  __shared__ float sB[32];

  // ---- stage W: state part (16 chunks/wave, hi+lo), x part (<=3 chunks, waves 0-2) ----
  s16x8 whi[16], wlo[16];
  s16x8 wxhi[3], wxlo[3];
  const int wcol = (ni << 5) + lcol;
  const int sb = ks << 4;            // state chunk base (k-split 16/16/16/16)
  #pragma unroll
  for (int i = 0; i < 16; ++i) {
    const int wr = 128 + (sb + i) * 16 + half8;
    const float* wp = W + (size_t)wr * N_HID + wcol;
    s16x8 hi, lo;
    #pragma unroll
    for (int j = 0; j < 8; ++j) {
      float f = wp[(size_t)j * N_HID];
      unsigned short h = f2bf(f);
      hi[j] = (short)h;
      lo[j] = (short)f2bf(f - bf2f(h));
    }
    whi[i] = hi; wlo[i] = lo;
  }
  if (ks < 3) {
    #pragma unroll
    for (int i = 0; i < 3; ++i) {   // ks2 stages 3, uses 2 (extra is in-bounds, unused)
      const int wr = (ks * 3 + i) * 16 + half8;
      const float* wp = W + (size_t)wr * N_HID + wcol;
      s16x8 hi, lo;
      #pragma unroll
      for (int j = 0; j < 8; ++j) {
        float f = wp[(size_t)j * N_HID];
        unsigned short h = f2bf(f);
        hi[j] = (short)h;
        lo[j] = (short)f2bf(f - bf2f(h));
      }
      wxhi[i] = hi; wxlo[i] = lo;
    }
  }
  if (tid < 32) sB[tid] = bias[(ni << 5) + tid];

  // ---- per-thread fp32 state (4 cols each), zero-publish buffer 0 ----
  const int e0   = tid << 2;
  const int rowL = e0 >> 5, c0 = e0 & 31;
  const int rowG = (mi << 5) + rowL;
  const int colG = (ni << 5) + c0;
  f32x4 hz = {0.f, 0.f, 0.f, 0.f};
  f32x4 hy = {0.f, 0.f, 0.f, 0.f};
  {
    u16x4 zh = {0, 0, 0, 0};
    pub8(Hbf + (size_t)rowG * 1024 + colG, zh);
    pub8(Hbf + (size_t)rowG * 1024 + 512 + colG, zh);
  }
  __syncthreads();   // drains vmcnt: zero-publishes acked at coherence point
  if (tid == 0)
    __hip_atomic_store(&gflags[ni], 1u, __ATOMIC_RELAXED, __HIP_MEMORY_SCOPE_AGENT);

  for (int t = 0; t < T_STEPS; ++t) {
    const unsigned short* rbuf = Hbf + (size_t)(t & 1) * (256 * 1024);
    unsigned short*       wbuf = Hbf + (size_t)((t & 1) ^ 1) * (256 * 1024);
    const u64* hrow = (const u64*)(rbuf + (size_t)rowA * 1024);

    f32x16 acc = {};
    // ---- overlap: waves 0-2 do the x-part (no state dep); wave 3 polls ----
    if (ks == 3) {
      const unsigned ep = (unsigned)t + 1u;
      const int l = lane & 15;
      for (;;) {
        unsigned v = __hip_atomic_load(&gflags[l], __ATOMIC_RELAXED, __HIP_MEMORY_SCOPE_AGENT);
        if (__ballot(v >= ep) == ~0ull) break;
        __builtin_amdgcn_s_sleep(2);   // backoff: cut poll-storm fabric pressure
      }
    } else {
      const float* xrow = x + (size_t)t * (BATCH * N_INP) + (size_t)rowA * N_INP;
      if (ks == 0)      xpart<0, 3>(xrow, half8, wxhi, wxlo, acc);
      else if (ks == 1) xpart<3, 3>(xrow, half8, wxhi, wxlo, acc);
      else              xpart<6, 2>(xrow, half8, wxhi, wxlo, acc);
    }
    __syncthreads();   // join: flags seen -> sc1 state loads below get fresh data

    // ---- state part: 16 chunks/wave via sc1 loads (no fence, no L2 pollution) ----
    #pragma unroll
    for (int i = 0; i < 16; ++i) {
      const int off = (((sb + i) << 4) + half8) >> 2;   // u64 index into row
      u64 q0 = ld8(hrow + off);
      u64 q1 = ld8(hrow + off + 1);
      union { u64 q[2]; s16x8 s; } u; u.q[0] = q0; u.q[1] = q1;
      acc = __builtin_amdgcn_mfma_f32_32x32x16_bf16(u.s, whi[i], acc, 0, 0, 0);
      acc = __builtin_amdgcn_mfma_f32_32x32x16_bf16(u.s, wlo[i], acc, 0, 0, 0);
    }

    // ---- K-split partials (C/D layout: col=lane&31, row=(r&3)+8*(r>>2)+4*half) ----
    #pragma unroll
    for (int r = 0; r < 16; ++r) {
      const int rowL_r = (r & 3) + ((r >> 2) << 3) + (half << 2);
      sC[ks][rowL_r * 32 + lcol] = acc[r];
    }
    __syncthreads();

    // ---- reduce + tanh + state update + publish (sc1 stores, wave-contiguous) ----
    {
      f32x4 s = *reinterpret_cast<f32x4*>(&sC[0][e0]);
      s += *reinterpret_cast<f32x4*>(&sC[1][e0]);
      s += *reinterpret_cast<f32x4*>(&sC[2][e0]);
      s += *reinterpret_cast<f32x4*>(&sC[3][e0]);
      u16x4 pz, py;
      #pragma unroll
      for (int j = 0; j < 4; ++j) {
        float pre = tanhf(s[j] + sB[c0 + j]);
        float z = hz[j] + DT_C * (pre - GAMMA_C * hy[j] - EPS_C * hz[j]);
        float y = hy[j] + DT_C * z;
        hz[j] = z; hy[j] = y;
        pz[j] = f2bf(z); py[j] = f2bf(y);
      }
      pub8(wbuf + (size_t)rowG * 1024 + colG, pz);
      pub8(wbuf + (size_t)rowG * 1024 + 512 + colG, py);
    }
    __syncthreads();   // drains vmcnt: publishes acked before flag
    if (tid == 0)
      __hip_atomic_store(&gflags[ni], (unsigned)t + 2u, __ATOMIC_RELAXED, __HIP_MEMORY_SCOPE_AGENT);
  }

  if (Hy32 != nullptr)
    *reinterpret_cast<f32x4*>(Hy32 + (size_t)rowG * 512 + colG) = hy;
}

// out[b][c] = sum_k hy[b][k] * Wout[k][c] + bout[c]
__global__ void cornn_out_kernel(const float* __restrict__ Hy32,
                                 const unsigned short* __restrict__ HbfFinal,
                                 const float* __restrict__ Wout,
                                 const float* __restrict__ bout,
                                 float* __restrict__ out) {
  const int b = blockIdx.x;
  const int lane = threadIdx.x;   // 64 threads
  float a[N_OUT];
  #pragma unroll
  for (int c = 0; c < N_OUT; ++c) a[c] = 0.f;
  #pragma unroll
  for (int j = 0; j < 8; ++j) {
    const int k = lane + (j << 6);
    const float h = Hy32 ? Hy32[(size_t)b * N_HID + k]
                         : bf2f(HbfFinal[(size_t)b * 1024 + 512 + k]);
    const float* wr = Wout + (size_t)k * N_OUT;
    #pragma unroll
    for (int c = 0; c < N_OUT; ++c) a[c] += h * wr[c];
  }
  #pragma unroll
  for (int c = 0; c < N_OUT; ++c) {
    float v = a[c];
    for (int off = 32; off > 0; off >>= 1) v += __shfl_down(v, off, 64);
    if (lane == 0) out[(size_t)b * N_OUT + c] = v + bout[c];
  }
}

extern "C" void kernel_launch(void* const* d_in, const int* in_sizes, int n_in,
                              void* d_out, int out_size, void* d_ws, size_t ws_size,
                              hipStream_t stream) {
  (void)in_sizes; (void)n_in; (void)out_size;
  const float* x    = (const float*)d_in[0];
  const float* W    = (const float*)d_in[1];
  const float* bias = (const float*)d_in[2];
  const float* Wout = (const float*)d_in[3];
  const float* bout = (const float*)d_in[4];

  char* ws = (char*)d_ws;
  unsigned*       flags = (unsigned*)ws;                      // 4 KiB flag area
  unsigned short* Hbf   = (unsigned short*)(ws + 4096);       // 2 x 256 x 1024 bf16 = 1 MiB
  float*          Hy32  = (float*)(ws + 4096 + (size_t)2 * 256 * 1024 * 2);
  const size_t needed = 4096 + (size_t)2 * 256 * 1024 * 2 + (size_t)256 * 512 * 4;
  float* hyPtr = (ws_size >= needed) ? Hy32 : nullptr;

  hipMemsetAsync(flags, 0, 4096, stream);   // flags = 0 (ws is re-poisoned each launch)

  cornn_kernel<<<dim3(NWG), dim3(WG_THREADS), 0, stream>>>(x, W, bias, Hbf, hyPtr, flags);

  cornn_out_kernel<<<dim3(BATCH), dim3(64), 0, stream>>>(hyPtr, Hbf, Wout, bout,
                                                         (float*)d_out);
}

// Round 6
// 2367.336 us; speedup vs baseline: 4.3418x; 1.3417x over previous
//
#include <hip/hip_runtime.h>

#define T_STEPS 512
#define BATCH   256
#define N_INP   128
#define N_HID   512
#define N_OUT   10

#define DT_C     0.042f
#define GAMMA_C  2.7f
#define EPS_C    4.7f

#define NWG        128     // 8 m-groups (32 rows) x 16 n-tiles (32 cols)
#define GROUP_WGS  16      // WGs per row-group (share one flag set)
#define WG_THREADS 256

typedef short          s16x8  __attribute__((ext_vector_type(8)));
typedef float          f32x16 __attribute__((ext_vector_type(16)));
typedef float          f32x4  __attribute__((ext_vector_type(4)));
typedef unsigned short u16x4  __attribute__((ext_vector_type(4)));
typedef unsigned long long u64;

__device__ inline unsigned short f2bf(float f) {
  union { float f; unsigned u; } v; v.f = f;
  unsigned r = v.u + 0x7fffu + ((v.u >> 16) & 1u);   // RNE
  return (unsigned short)(r >> 16);
}
__device__ inline float bf2f(unsigned short h) {
  union { unsigned u; float f; } v; v.u = ((unsigned)h) << 16;
  return v.f;
}

// agent-scope relaxed store = write-through to the coherence point (IC).
__device__ inline void pub8(unsigned short* p, u16x4 v) {
  union { u16x4 v; u64 q; } u; u.v = v;
  __hip_atomic_store((u64*)p, u.q, __ATOMIC_RELAXED, __HIP_MEMORY_SCOPE_AGENT);
}

// x-part: chunks CI0..CI0+CNT-1 of the fp32 input, hi/lo bf16 split.
template<int CI0, int CNT>
__device__ inline void xpart(const float* xrow, int half8,
                             const s16x8* wxhi, const s16x8* wxlo, f32x16& acc) {
  #pragma unroll
  for (int i = 0; i < CNT; ++i) {
    const float* xp = xrow + (CI0 + i) * 16 + half8;
    f32x4 a0 = *reinterpret_cast<const f32x4*>(xp);
    f32x4 a1 = *reinterpret_cast<const f32x4*>(xp + 4);
    s16x8 ahi, alo;
    #pragma unroll
    for (int j = 0; j < 4; ++j) {
      float f0 = a0[j], f1 = a1[j];
      unsigned short h0 = f2bf(f0), h1 = f2bf(f1);
      ahi[j]     = (short)h0;  ahi[j + 4] = (short)h1;
      alo[j]     = (short)f2bf(f0 - bf2f(h0));
      alo[j + 4] = (short)f2bf(f1 - bf2f(h1));
    }
    acc = __builtin_amdgcn_mfma_f32_32x32x16_bf16(ahi, wxhi[i], acc, 0, 0, 0);
    acc = __builtin_amdgcn_mfma_f32_32x32x16_bf16(ahi, wxlo[i], acc, 0, 0, 0);
    acc = __builtin_amdgcn_mfma_f32_32x32x16_bf16(alo, wxhi[i], acc, 0, 0, 0);
  }
}

// Persistent recurrent kernel (plain launch; 128 blocks <= 256 CUs => co-resident).
// Hbf: double-buffered published state, bf16 [2][256][1024]; col c<512 = hz[c]
//      (W row 128+c), col 512+c = hy[c] (W row 640+c).
__global__ __launch_bounds__(WG_THREADS, 1) void cornn_kernel(
    const float* __restrict__ x, const float* __restrict__ W,
    const float* __restrict__ bias, unsigned short* __restrict__ Hbf,
    float* __restrict__ Hy32, unsigned* __restrict__ flags_ws) {
  const int tid   = threadIdx.x;
  const int lane  = tid & 63;
  const int ks    = tid >> 6;        // wave id 0..3
  const int half  = lane >> 5;       // A/B frag k-half
  const int half8 = half << 3;
  const int lcol  = lane & 31;
  const int mi    = blockIdx.x & 7;  // row group (XCD-aligned: blockIdx%8)
  const int ni    = blockIdx.x >> 3; // col tile
  const int rowA  = (mi << 5) + lcol;

  unsigned* gflags = flags_ws + mi * 64;   // 16 dwords per group, 256B stride

  __shared__ float sC[4][1024];   // K-split partials, 16 KB
  __shared__ float sB[32];

  // ---- stage W: state part (16 chunks/wave, hi+lo), x part (<=3 chunks, waves 0-2) ----
  s16x8 whi[16], wlo[16];
  s16x8 wxhi[3], wxlo[3];
  const int wcol = (ni << 5) + lcol;
  const int sb = ks << 4;            // state chunk base (k-split 16/16/16/16)
  #pragma unroll
  for (int i = 0; i < 16; ++i) {
    const int wr = 128 + (sb + i) * 16 + half8;
    const float* wp = W + (size_t)wr * N_HID + wcol;
    s16x8 hi, lo;
    #pragma unroll
    for (int j = 0; j < 8; ++j) {
      float f = wp[(size_t)j * N_HID];
      unsigned short h = f2bf(f);
      hi[j] = (short)h;
      lo[j] = (short)f2bf(f - bf2f(h));
    }
    whi[i] = hi; wlo[i] = lo;
  }
  if (ks < 3) {
    #pragma unroll
    for (int i = 0; i < 3; ++i) {   // ks2 stages 3, uses 2 (extra is in-bounds, unused)
      const int wr = (ks * 3 + i) * 16 + half8;
      const float* wp = W + (size_t)wr * N_HID + wcol;
      s16x8 hi, lo;
      #pragma unroll
      for (int j = 0; j < 8; ++j) {
        float f = wp[(size_t)j * N_HID];
        unsigned short h = f2bf(f);
        hi[j] = (short)h;
        lo[j] = (short)f2bf(f - bf2f(h));
      }
      wxhi[i] = hi; wxlo[i] = lo;
    }
  }
  if (tid < 32) sB[tid] = bias[(ni << 5) + tid];

  // ---- per-thread fp32 state (4 cols each) ----
  const int e0   = tid << 2;
  const int rowL = e0 >> 5, c0 = e0 & 31;
  const int rowG = (mi << 5) + rowL;
  const int colG = (ni << 5) + c0;
  f32x4 hz = {0.f, 0.f, 0.f, 0.f};
  f32x4 hy = {0.f, 0.f, 0.f, 0.f};

  // state-read base pointers (per lane), one per buffer
  const unsigned short* hb[2];
  hb[0] = Hbf + (size_t)rowA * 1024 + (sb << 4) + half8;
  hb[1] = hb[0] + 256 * 1024;
  // publish pointers (per thread), one per buffer
  unsigned short* wz[2];
  unsigned short* wy[2];
  wz[0] = Hbf + (size_t)rowG * 1024 + colG;       wz[1] = wz[0] + 256 * 1024;
  wy[0] = wz[0] + 512;                            wy[1] = wz[1] + 512;

  __syncthreads();   // sB visible

  for (int t = 0; t < T_STEPS; ++t) {
    f32x16 acc = {};

    // ---- x-part (no state dep): waves 0-2; overlaps producers' publish latency ----
    if (ks < 3) {
      const float* xrow = x + (size_t)t * (BATCH * N_INP) + (size_t)rowA * N_INP;
      if (ks == 0)      xpart<0, 3>(xrow, half8, wxhi, wxlo, acc);
      else if (ks == 1) xpart<3, 3>(xrow, half8, wxhi, wxlo, acc);
      else              xpart<6, 2>(xrow, half8, wxhi, wxlo, acc);
    }

    if (t > 0) {
      // ---- per-wave poll (skip own flag; no join barrier) ----
      const unsigned ep = (unsigned)t;
      const int l = lane & 15;
      for (;;) {
        unsigned v = __hip_atomic_load(&gflags[l], __ATOMIC_RELAXED, __HIP_MEMORY_SCOPE_AGENT);
        if (__ballot((lane >= 16) || (l == ni) || (v >= ep)) == ~0ull) break;
        __builtin_amdgcn_s_sleep(2);
      }

      // ---- state part: 16 coherent 16B loads + waitcnt fused in ONE asm block.
      // (Separate asm statements are unsafe: the backend doesn't model loads
      // hidden in asm, so MFMAs could be scheduled before the manual waitcnt.
      // Fusing loads+waitcnt makes every use data-depend on the completed wait.
      // Outputs are earlyclobber: they must not alias the address pair.) ----
      const unsigned short* hp = hb[t & 1];
      f32x4 hbuf[16];
      asm volatile(
        "global_load_dwordx4 %0, %16, off sc0 sc1\n\t"
        "global_load_dwordx4 %1, %16, off offset:32 sc0 sc1\n\t"
        "global_load_dwordx4 %2, %16, off offset:64 sc0 sc1\n\t"
        "global_load_dwordx4 %3, %16, off offset:96 sc0 sc1\n\t"
        "global_load_dwordx4 %4, %16, off offset:128 sc0 sc1\n\t"
        "global_load_dwordx4 %5, %16, off offset:160 sc0 sc1\n\t"
        "global_load_dwordx4 %6, %16, off offset:192 sc0 sc1\n\t"
        "global_load_dwordx4 %7, %16, off offset:224 sc0 sc1\n\t"
        "global_load_dwordx4 %8, %16, off offset:256 sc0 sc1\n\t"
        "global_load_dwordx4 %9, %16, off offset:288 sc0 sc1\n\t"
        "global_load_dwordx4 %10, %16, off offset:320 sc0 sc1\n\t"
        "global_load_dwordx4 %11, %16, off offset:352 sc0 sc1\n\t"
        "global_load_dwordx4 %12, %16, off offset:384 sc0 sc1\n\t"
        "global_load_dwordx4 %13, %16, off offset:416 sc0 sc1\n\t"
        "global_load_dwordx4 %14, %16, off offset:448 sc0 sc1\n\t"
        "global_load_dwordx4 %15, %16, off offset:480 sc0 sc1\n\t"
        "s_waitcnt vmcnt(0)"
        : "=&v"(hbuf[0]),  "=&v"(hbuf[1]),  "=&v"(hbuf[2]),  "=&v"(hbuf[3]),
          "=&v"(hbuf[4]),  "=&v"(hbuf[5]),  "=&v"(hbuf[6]),  "=&v"(hbuf[7]),
          "=&v"(hbuf[8]),  "=&v"(hbuf[9]),  "=&v"(hbuf[10]), "=&v"(hbuf[11]),
          "=&v"(hbuf[12]), "=&v"(hbuf[13]), "=&v"(hbuf[14]), "=&v"(hbuf[15])
        : "v"(hp)
        : "memory");
      #pragma unroll
      for (int i = 0; i < 16; ++i) {
        union { f32x4 f; s16x8 s; } u; u.f = hbuf[i];
        acc = __builtin_amdgcn_mfma_f32_32x32x16_bf16(u.s, whi[i], acc, 0, 0, 0);
        acc = __builtin_amdgcn_mfma_f32_32x32x16_bf16(u.s, wlo[i], acc, 0, 0, 0);
      }
    }

    // ---- K-split partials (C/D layout: col=lane&31, row=(r&3)+8*(r>>2)+4*half) ----
    #pragma unroll
    for (int r = 0; r < 16; ++r) {
      const int rowL_r = (r & 3) + ((r >> 2) << 3) + (half << 2);
      sC[ks][rowL_r * 32 + lcol] = acc[r];
    }
    __syncthreads();

    // ---- reduce + tanh + state update + publish ----
    {
      f32x4 s = *reinterpret_cast<f32x4*>(&sC[0][e0]);
      s += *reinterpret_cast<f32x4*>(&sC[1][e0]);
      s += *reinterpret_cast<f32x4*>(&sC[2][e0]);
      s += *reinterpret_cast<f32x4*>(&sC[3][e0]);
      u16x4 pz, py;
      #pragma unroll
      for (int j = 0; j < 4; ++j) {
        float pre = tanhf(s[j] + sB[c0 + j]);
        float z = hz[j] + DT_C * (pre - GAMMA_C * hy[j] - EPS_C * hz[j]);
        float y = hy[j] + DT_C * z;
        hz[j] = z; hy[j] = y;
        pz[j] = f2bf(z); py[j] = f2bf(y);
      }
      const int wb = (t & 1) ^ 1;
      pub8(wz[wb], pz);
      pub8(wy[wb], py);
    }
    __syncthreads();   // drains vmcnt: publishes acked at coherence point before flag
    if (tid == 0)
      __hip_atomic_store(&gflags[ni], (unsigned)t + 1u, __ATOMIC_RELAXED, __HIP_MEMORY_SCOPE_AGENT);
  }

  if (Hy32 != nullptr)
    *reinterpret_cast<f32x4*>(Hy32 + (size_t)rowG * 512 + colG) = hy;
}

// out[b][c] = sum_k hy[b][k] * Wout[k][c] + bout[c]
__global__ void cornn_out_kernel(const float* __restrict__ Hy32,
                                 const unsigned short* __restrict__ HbfFinal,
                                 const float* __restrict__ Wout,
                                 const float* __restrict__ bout,
                                 float* __restrict__ out) {
  const int b = blockIdx.x;
  const int lane = threadIdx.x;   // 64 threads
  float a[N_OUT];
  #pragma unroll
  for (int c = 0; c < N_OUT; ++c) a[c] = 0.f;
  #pragma unroll
  for (int j = 0; j < 8; ++j) {
    const int k = lane + (j << 6);
    const float h = Hy32 ? Hy32[(size_t)b * N_HID + k]
                         : bf2f(HbfFinal[(size_t)b * 1024 + 512 + k]);
    const float* wr = Wout + (size_t)k * N_OUT;
    #pragma unroll
    for (int c = 0; c < N_OUT; ++c) a[c] += h * wr[c];
  }
  #pragma unroll
  for (int c = 0; c < N_OUT; ++c) {
    float v = a[c];
    for (int off = 32; off > 0; off >>= 1) v += __shfl_down(v, off, 64);
    if (lane == 0) out[(size_t)b * N_OUT + c] = v + bout[c];
  }
}

extern "C" void kernel_launch(void* const* d_in, const int* in_sizes, int n_in,
                              void* d_out, int out_size, void* d_ws, size_t ws_size,
                              hipStream_t stream) {
  (void)in_sizes; (void)n_in; (void)out_size;
  const float* x    = (const float*)d_in[0];
  const float* W    = (const float*)d_in[1];
  const float* bias = (const float*)d_in[2];
  const float* Wout = (const float*)d_in[3];
  const float* bout = (const float*)d_in[4];

  char* ws = (char*)d_ws;
  unsigned*       flags = (unsigned*)ws;                      // 4 KiB flag area
  unsigned short* Hbf   = (unsigned short*)(ws + 4096);       // 2 x 256 x 1024 bf16 = 1 MiB
  float*          Hy32  = (float*)(ws + 4096 + (size_t)2 * 256 * 1024 * 2);
  const size_t needed = 4096 + (size_t)2 * 256 * 1024 * 2 + (size_t)256 * 512 * 4;
  float* hyPtr = (ws_size >= needed) ? Hy32 : nullptr;

  hipMemsetAsync(flags, 0, 4096, stream);   // flags = 0 (ws is re-poisoned each launch)

  cornn_kernel<<<dim3(NWG), dim3(WG_THREADS), 0, stream>>>(x, W, bias, Hbf, hyPtr, flags);

  cornn_out_kernel<<<dim3(BATCH), dim3(64), 0, stream>>>(hyPtr, Hbf, Wout, bout,
                                                         (float*)d_out);
}

// Round 8
// 2284.540 us; speedup vs baseline: 4.4992x; 1.0362x over previous
//
#include <hip/hip_runtime.h>

#define T_STEPS 512
#define BATCH   256
#define N_INP   128
#define N_HID   512
#define N_OUT   10

#define DT_C     0.042f
#define GAMMA_C  2.7f
#define EPS_C    4.7f

#define NWG        64      // 8 m-groups (32 rows) x 8 n-tiles (64 cols)
#define GROUP_WGS  8       // WGs per row-group (share one flag set)
#define WG_THREADS 512     // 8 waves, 8-way K-split

typedef short          s16x8  __attribute__((ext_vector_type(8)));
typedef float          f32x16 __attribute__((ext_vector_type(16)));
typedef float          f32x4  __attribute__((ext_vector_type(4)));
typedef unsigned short u16x4  __attribute__((ext_vector_type(4)));
typedef unsigned long long u64;

__device__ inline unsigned short f2bf(float f) {
  union { float f; unsigned u; } v; v.f = f;
  unsigned r = v.u + 0x7fffu + ((v.u >> 16) & 1u);   // RNE
  return (unsigned short)(r >> 16);
}
__device__ inline float bf2f(unsigned short h) {
  union { unsigned u; float f; } v; v.u = ((unsigned)h) << 16;
  return v.f;
}

// agent-scope relaxed store: write-through to the coherence point (IC). Proven R4-R6.
__device__ inline void pub8(unsigned short* p, u16x4 v) {
  union { u16x4 v; u64 q; } u; u.v = v;
  __hip_atomic_store((u64*)p, u.q, __ATOMIC_RELAXED, __HIP_MEMORY_SCOPE_AGENT);
}

// 8 coherent 16B loads + waitcnt fused in ONE asm block (R6 lesson: the backend
// doesn't model asm loads, so the waitcnt must live in the same asm block every
// consumer data-depends on). Outputs earlyclobber vs the address pair.
#define STATE_LD8(HB, HP)                                                    \
  asm volatile(                                                              \
    "global_load_dwordx4 %0, %8, off sc0 sc1\n\t"                            \
    "global_load_dwordx4 %1, %8, off offset:32 sc0 sc1\n\t"                  \
    "global_load_dwordx4 %2, %8, off offset:64 sc0 sc1\n\t"                  \
    "global_load_dwordx4 %3, %8, off offset:96 sc0 sc1\n\t"                  \
    "global_load_dwordx4 %4, %8, off offset:128 sc0 sc1\n\t"                 \
    "global_load_dwordx4 %5, %8, off offset:160 sc0 sc1\n\t"                 \
    "global_load_dwordx4 %6, %8, off offset:192 sc0 sc1\n\t"                 \
    "global_load_dwordx4 %7, %8, off offset:224 sc0 sc1\n\t"                 \
    "s_waitcnt vmcnt(0)"                                                     \
    : "=&v"(HB[0]), "=&v"(HB[1]), "=&v"(HB[2]), "=&v"(HB[3]),                \
      "=&v"(HB[4]), "=&v"(HB[5]), "=&v"(HB[6]), "=&v"(HB[7])                 \
    : "v"(HP)                                                                \
    : "memory")

// Persistent recurrent kernel (plain launch; 64 blocks of 8 waves => 1 WG/CU,
// trivially co-resident).
// Hbf: double-buffered published state, bf16 [2][256][1024]; col c<512 = hz[c]
//      (W row 128+c), col 512+c = hy[c] (W row 640+c).
__global__ __launch_bounds__(WG_THREADS, 2) void cornn_kernel(
    const float* __restrict__ x, const float* __restrict__ W,
    const float* __restrict__ bias, unsigned short* __restrict__ Hbf,
    float* __restrict__ Hy32, unsigned* __restrict__ flags_ws) {
  const int tid   = threadIdx.x;
  const int lane  = tid & 63;
  const int ks    = tid >> 6;        // wave id 0..7 (8-way K-split)
  const int half  = lane >> 5;       // A/B frag k-half
  const int half8 = half << 3;
  const int lcol  = lane & 31;
  const int mi    = blockIdx.x & 7;  // row group
  const int ni    = blockIdx.x >> 3; // 64-col tile, 0..7
  const int rowA  = (mi << 5) + lcol;

  unsigned* gflags = flags_ws + mi * 64;   // 8 dwords used per group, 256B stride

  __shared__ float sC[8][2048];   // K-split partials (32 rows x 64 cols), 64 KB
  __shared__ float sB[64];

  // ---- stage W in registers: state 8 chunks/wave x 2 col-tiles (hi+lo),
  //      x 1 chunk/wave x 2 col-tiles (hi+lo) ----
  s16x8 whi0[8], wlo0[8], whi1[8], wlo1[8];
  s16x8 wxhi0, wxlo0, wxhi1, wxlo1;
  const int c0t = (ni << 6) + lcol;      // col tile 0
  const int c1t = c0t + 32;              // col tile 1
  #pragma unroll
  for (int i = 0; i < 8; ++i) {
    const int wr = 128 + (ks << 7) + i * 16 + half8;
    const float* wp0 = W + (size_t)wr * N_HID + c0t;
    s16x8 hi0, lo0, hi1, lo1;
    #pragma unroll
    for (int j = 0; j < 8; ++j) {
      float f0 = wp0[(size_t)j * N_HID];
      float f1 = wp0[(size_t)j * N_HID + 32];
      unsigned short h0 = f2bf(f0), h1 = f2bf(f1);
      hi0[j] = (short)h0;  lo0[j] = (short)f2bf(f0 - bf2f(h0));
      hi1[j] = (short)h1;  lo1[j] = (short)f2bf(f1 - bf2f(h1));
    }
    whi0[i] = hi0; wlo0[i] = lo0; whi1[i] = hi1; wlo1[i] = lo1;
  }
  {
    const int wr = (ks << 4) + half8;    // x chunk ks: k = ks*16
    const float* wp0 = W + (size_t)wr * N_HID + c0t;
    s16x8 hi0, lo0, hi1, lo1;
    #pragma unroll
    for (int j = 0; j < 8; ++j) {
      float f0 = wp0[(size_t)j * N_HID];
      float f1 = wp0[(size_t)j * N_HID + 32];
      unsigned short h0 = f2bf(f0), h1 = f2bf(f1);
      hi0[j] = (short)h0;  lo0[j] = (short)f2bf(f0 - bf2f(h0));
      hi1[j] = (short)h1;  lo1[j] = (short)f2bf(f1 - bf2f(h1));
    }
    wxhi0 = hi0; wxlo0 = lo0; wxhi1 = hi1; wxlo1 = lo1;
  }
  if (tid < 64) sB[tid] = bias[(ni << 6) + tid];

  // ---- per-thread fp32 state (4 cols each; 512 thr x 4 = 32 rows x 64 cols) ----
  const int e0   = tid << 2;
  const int rowL = e0 >> 6, c0 = e0 & 63;
  const int rowG = (mi << 5) + rowL;
  const int colG = (ni << 6) + c0;
  f32x4 hz = {0.f, 0.f, 0.f, 0.f};
  f32x4 hy = {0.f, 0.f, 0.f, 0.f};

  // state-read base pointers (per lane), one per buffer
  const unsigned short* hb2[2];
  hb2[0] = Hbf + (size_t)rowA * 1024 + (ks << 7) + half8;
  hb2[1] = hb2[0] + 256 * 1024;
  // publish pointers (per thread), one per buffer
  unsigned short* wz[2];
  unsigned short* wy[2];
  wz[0] = Hbf + (size_t)rowG * 1024 + colG;       wz[1] = wz[0] + 256 * 1024;
  wy[0] = wz[0] + 512;                            wy[1] = wz[1] + 512;

  __syncthreads();   // sB visible

  for (int t = 0; t < T_STEPS; ++t) {
    f32x16 acc0 = {};
    f32x16 acc1 = {};

    // ---- x-part (no state dep): every wave does its 16-k chunk ----
    {
      const float* xp = x + (size_t)t * (BATCH * N_INP) + (size_t)rowA * N_INP
                        + (ks << 4) + half8;
      f32x4 a0 = *reinterpret_cast<const f32x4*>(xp);
      f32x4 a1 = *reinterpret_cast<const f32x4*>(xp + 4);
      s16x8 ahi, alo;
      #pragma unroll
      for (int j = 0; j < 4; ++j) {
        float f0 = a0[j], f1 = a1[j];
        unsigned short h0 = f2bf(f0), h1 = f2bf(f1);
        ahi[j]     = (short)h0;  ahi[j + 4] = (short)h1;
        alo[j]     = (short)f2bf(f0 - bf2f(h0));
        alo[j + 4] = (short)f2bf(f1 - bf2f(h1));
      }
      acc0 = __builtin_amdgcn_mfma_f32_32x32x16_bf16(ahi, wxhi0, acc0, 0, 0, 0);
      acc0 = __builtin_amdgcn_mfma_f32_32x32x16_bf16(ahi, wxlo0, acc0, 0, 0, 0);
      acc0 = __builtin_amdgcn_mfma_f32_32x32x16_bf16(alo, wxhi0, acc0, 0, 0, 0);
      acc1 = __builtin_amdgcn_mfma_f32_32x32x16_bf16(ahi, wxhi1, acc1, 0, 0, 0);
      acc1 = __builtin_amdgcn_mfma_f32_32x32x16_bf16(ahi, wxlo1, acc1, 0, 0, 0);
      acc1 = __builtin_amdgcn_mfma_f32_32x32x16_bf16(alo, wxhi1, acc1, 0, 0, 0);
    }

    if (t > 0) {
      // ---- per-wave poll of the 8 group flags (skip own; no join barrier) ----
      const unsigned ep = (unsigned)t;
      const int l = lane & 7;
      for (;;) {
        unsigned v = __hip_atomic_load(&gflags[l], __ATOMIC_RELAXED, __HIP_MEMORY_SCOPE_AGENT);
        if (__ballot((lane >= 8) | (l == ni) | (v >= ep)) == ~0ull) break;
        __builtin_amdgcn_s_sleep(2);
      }

      // ---- state part: 8 pipelined coherent 16B loads, ONE round-trip ----
      const unsigned short* hp = hb2[t & 1];
      f32x4 hbuf[8];
      STATE_LD8(hbuf, hp);
      #pragma unroll
      for (int i = 0; i < 8; ++i) {
        union { f32x4 f; s16x8 s; } u; u.f = hbuf[i];
        acc0 = __builtin_amdgcn_mfma_f32_32x32x16_bf16(u.s, whi0[i], acc0, 0, 0, 0);
        acc0 = __builtin_amdgcn_mfma_f32_32x32x16_bf16(u.s, wlo0[i], acc0, 0, 0, 0);
        acc1 = __builtin_amdgcn_mfma_f32_32x32x16_bf16(u.s, whi1[i], acc1, 0, 0, 0);
        acc1 = __builtin_amdgcn_mfma_f32_32x32x16_bf16(u.s, wlo1[i], acc1, 0, 0, 0);
      }
    }

    // ---- K-split partials (C/D layout: col=lane&31, row=(r&3)+8*(r>>2)+4*half) ----
    #pragma unroll
    for (int r = 0; r < 16; ++r) {
      const int rowL_r = (r & 3) + ((r >> 2) << 3) + (half << 2);
      sC[ks][rowL_r * 64 + lcol]      = acc0[r];
      sC[ks][rowL_r * 64 + 32 + lcol] = acc1[r];
    }
    __syncthreads();

    // ---- reduce (8-way) + tanh + state update + publish ----
    {
      f32x4 s = *reinterpret_cast<f32x4*>(&sC[0][e0]);
      #pragma unroll
      for (int w = 1; w < 8; ++w) s += *reinterpret_cast<f32x4*>(&sC[w][e0]);
      u16x4 pz, py;
      #pragma unroll
      for (int j = 0; j < 4; ++j) {
        float pre = tanhf(s[j] + sB[c0 + j]);
        float z = hz[j] + DT_C * (pre - GAMMA_C * hy[j] - EPS_C * hz[j]);
        float y = hy[j] + DT_C * z;
        hz[j] = z; hy[j] = y;
        pz[j] = f2bf(z); py[j] = f2bf(y);
      }
      const int wb = (t & 1) ^ 1;
      pub8(wz[wb], pz);
      pub8(wy[wb], py);
    }
    __syncthreads();   // drains vmcnt: publishes acked at coherence point before flag
    if (tid == 0)
      __hip_atomic_store(&gflags[ni], (unsigned)t + 1u, __ATOMIC_RELAXED, __HIP_MEMORY_SCOPE_AGENT);
  }

  if (Hy32 != nullptr)
    *reinterpret_cast<f32x4*>(Hy32 + (size_t)rowG * 512 + colG) = hy;
}

// out[b][c] = sum_k hy[b][k] * Wout[k][c] + bout[c]
__global__ void cornn_out_kernel(const float* __restrict__ Hy32,
                                 const unsigned short* __restrict__ HbfFinal,
                                 const float* __restrict__ Wout,
                                 const float* __restrict__ bout,
                                 float* __restrict__ out) {
  const int b = blockIdx.x;
  const int lane = threadIdx.x;   // 64 threads
  float a[N_OUT];
  #pragma unroll
  for (int c = 0; c < N_OUT; ++c) a[c] = 0.f;
  #pragma unroll
  for (int j = 0; j < 8; ++j) {
    const int k = lane + (j << 6);
    const float h = Hy32 ? Hy32[(size_t)b * N_HID + k]
                         : bf2f(HbfFinal[(size_t)b * 1024 + 512 + k]);
    const float* wr = Wout + (size_t)k * N_OUT;
    #pragma unroll
    for (int c = 0; c < N_OUT; ++c) a[c] += h * wr[c];
  }
  #pragma unroll
  for (int c = 0; c < N_OUT; ++c) {
    float v = a[c];
    for (int off = 32; off > 0; off >>= 1) v += __shfl_down(v, off, 64);
    if (lane == 0) out[(size_t)b * N_OUT + c] = v + bout[c];
  }
}

extern "C" void kernel_launch(void* const* d_in, const int* in_sizes, int n_in,
                              void* d_out, int out_size, void* d_ws, size_t ws_size,
                              hipStream_t stream) {
  (void)in_sizes; (void)n_in; (void)out_size;
  const float* x    = (const float*)d_in[0];
  const float* W    = (const float*)d_in[1];
  const float* bias = (const float*)d_in[2];
  const float* Wout = (const float*)d_in[3];
  const float* bout = (const float*)d_in[4];

  char* ws = (char*)d_ws;
  unsigned*       flags = (unsigned*)ws;                      // 4 KiB flag area
  unsigned short* Hbf   = (unsigned short*)(ws + 4096);       // 2 x 256 x 1024 bf16 = 1 MiB
  float*          Hy32  = (float*)(ws + 4096 + (size_t)2 * 256 * 1024 * 2);
  const size_t needed = 4096 + (size_t)2 * 256 * 1024 * 2 + (size_t)256 * 512 * 4;
  float* hyPtr = (ws_size >= needed) ? Hy32 : nullptr;

  hipMemsetAsync(flags, 0, 4096, stream);   // flags = 0 (ws is re-poisoned each launch)

  cornn_kernel<<<dim3(NWG), dim3(WG_THREADS), 0, stream>>>(x, W, bias, Hbf, hyPtr, flags);

  cornn_out_kernel<<<dim3(BATCH), dim3(64), 0, stream>>>(hyPtr, Hbf, Wout, bout,
                                                         (float*)d_out);
}